// Round 1
// baseline (773.905 us; speedup 1.0000x reference)
//
#include <hip/hip_runtime.h>
#include <cstdint>
#include <cstddef>

#define B_    4096
#define H_    1024
#define NOBS  128
#define NDIR  64
#define MAXIT 10
#define LRI   1e-3f
#define TOLC  1e-3

// ---------------------------------------------------------------------------
// Generic tiled fp32 GEMM:
//   WT=1: O[m,n] = sum_k W[n*ldW + k] * S[m*ldS + k]   (W row-major [N,K])
//   WT=0: O[m,n] = sum_k W[k*ldW + n] * S[m*ldS + k]   (W row-major [K,N])
// EPI=0: store acc
// EPI=1: store relu(acc + Win[n, dirs[m]])           (drive fused)
// EPI=3: store Cin + LRI*((Rin - Cin) + acc)         (Rin may alias O)
// gate: if non-null and *gate==0, kernel is a no-op.
// ---------------------------------------------------------------------------
template<int BM, int BN, int BK, int TM, int TN, int WT, int EPI>
__global__ __launch_bounds__(256)
void gemm_k(const float* __restrict__ S, int ldS,
            const float* __restrict__ W, int ldW,
            float* O, int ldO, int K,
            const int* __restrict__ dirs, const float* __restrict__ WinP,
            const float* Cin, const float* Rin,
            const int* gate)
{
    if (gate && *gate == 0) return;

    __shared__ float sS[BK][BM + 4];
    __shared__ float sW[BK][BN + 4];

    const int tid = threadIdx.x;
    const int m0 = blockIdx.y * BM;
    const int n0 = blockIdx.x * BN;
    constexpr int NTC = BN / TN;
    const int tr = tid / NTC;
    const int tc = tid % NTC;

    float acc[TM][TN];
#pragma unroll
    for (int i = 0; i < TM; ++i)
#pragma unroll
        for (int j = 0; j < TN; ++j) acc[i][j] = 0.f;

    for (int k0 = 0; k0 < K; k0 += BK) {
        // stage S tile (transposed: sS[k][m])
#pragma unroll
        for (int t = tid; t < BM * BK / 4; t += 256) {
            const int r  = t / (BK / 4);
            const int c4 = (t % (BK / 4)) * 4;
            const float4 v = *(const float4*)(S + (size_t)(m0 + r) * ldS + k0 + c4);
            sS[c4 + 0][r] = v.x; sS[c4 + 1][r] = v.y;
            sS[c4 + 2][r] = v.z; sS[c4 + 3][r] = v.w;
        }
        if (WT) {
#pragma unroll
            for (int t = tid; t < BN * BK / 4; t += 256) {
                const int r  = t / (BK / 4);
                const int c4 = (t % (BK / 4)) * 4;
                const float4 v = *(const float4*)(W + (size_t)(n0 + r) * ldW + k0 + c4);
                sW[c4 + 0][r] = v.x; sW[c4 + 1][r] = v.y;
                sW[c4 + 2][r] = v.z; sW[c4 + 3][r] = v.w;
            }
        } else {
#pragma unroll
            for (int t = tid; t < BK * BN / 4; t += 256) {
                const int r  = t / (BN / 4);
                const int c4 = (t % (BN / 4)) * 4;
                *(float4*)(&sW[r][c4]) =
                    *(const float4*)(W + (size_t)(k0 + r) * ldW + n0 + c4);
            }
        }
        __syncthreads();

#pragma unroll
        for (int k = 0; k < BK; ++k) {
            float a[TM], b[TN];
#pragma unroll
            for (int i = 0; i < TM; i += 4) {
                const float4 v = *(const float4*)(&sS[k][tr * TM + i]);
                a[i] = v.x; a[i + 1] = v.y; a[i + 2] = v.z; a[i + 3] = v.w;
            }
#pragma unroll
            for (int j = 0; j < TN; j += 4) {
                const float4 v = *(const float4*)(&sW[k][tc * TN + j]);
                b[j] = v.x; b[j + 1] = v.y; b[j + 2] = v.z; b[j + 3] = v.w;
            }
#pragma unroll
            for (int i = 0; i < TM; ++i)
#pragma unroll
                for (int j = 0; j < TN; ++j)
                    acc[i][j] = fmaf(a[i], b[j], acc[i][j]);
        }
        __syncthreads();
    }

    // epilogue (float4 stores)
#pragma unroll
    for (int i = 0; i < TM; ++i) {
        const int m = m0 + tr * TM + i;
#pragma unroll
        for (int j = 0; j < TN; j += 4) {
            const int n = n0 + tc * TN + j;
            const size_t idx = (size_t)m * ldO + n;
            float4 v;
            v.x = acc[i][j]; v.y = acc[i][j + 1]; v.z = acc[i][j + 2]; v.w = acc[i][j + 3];
            if (EPI == 1) {
                const int dd = dirs[m];
                v.x = fmaxf(v.x + WinP[(size_t)(n + 0) * NDIR + dd], 0.f);
                v.y = fmaxf(v.y + WinP[(size_t)(n + 1) * NDIR + dd], 0.f);
                v.z = fmaxf(v.z + WinP[(size_t)(n + 2) * NDIR + dd], 0.f);
                v.w = fmaxf(v.w + WinP[(size_t)(n + 3) * NDIR + dd], 0.f);
            } else if (EPI == 3) {
                const float4 cv = *(const float4*)(Cin + idx);
                const float4 rv = *(const float4*)(Rin + idx);
                v.x = cv.x + LRI * ((rv.x - cv.x) + v.x);
                v.y = cv.y + LRI * ((rv.y - cv.y) + v.y);
                v.z = cv.z + LRI * ((rv.z - cv.z) + v.z);
                v.w = cv.w + LRI * ((rv.w - cv.w) + v.w);
            }
            *(float4*)(O + idx) = v;
        }
    }
}

// row-wise L2 normalize: Cout[b,:] = T[b,:] / (||T[b,:]|| + 1e-6)
__global__ __launch_bounds__(256)
void rownorm_k(const float* __restrict__ T, float* __restrict__ Cout, const int* gate)
{
    if (gate && *gate == 0) return;
    __shared__ float wsum[4];
    const int b = blockIdx.x;
    const float4 v = ((const float4*)(T + (size_t)b * H_))[threadIdx.x];
    float ss = v.x * v.x + v.y * v.y + v.z * v.z + v.w * v.w;
#pragma unroll
    for (int off = 32; off > 0; off >>= 1) ss += __shfl_down(ss, off, 64);
    const int lane = threadIdx.x & 63, wid = threadIdx.x >> 6;
    if (lane == 0) wsum[wid] = ss;
    __syncthreads();
    const float tot = wsum[0] + wsum[1] + wsum[2] + wsum[3];
    const float d = sqrtf(tot) + 1e-6f;
    float4 o;
    o.x = v.x / d; o.y = v.y / d; o.z = v.z / d; o.w = v.w / d;
    ((float4*)(Cout + (size_t)b * H_))[threadIdx.x] = o;
}

// softmax over 128 logits + softmax-Jacobian vector product. 1 wave = 1 row.
__global__ __launch_bounds__(256)
void softmax_jv_k(const float* __restrict__ L, const int* __restrict__ obs,
                  float* __restrict__ Jv, const int* gate)
{
    if (gate && *gate == 0) return;
    const int wid = threadIdx.x >> 6, lane = threadIdx.x & 63;
    const int b = blockIdx.x * 4 + wid;
    const float* lp = L + (size_t)b * NOBS;
    const float x0 = lp[lane], x1 = lp[lane + 64];
    float mx = fmaxf(x0, x1);
#pragma unroll
    for (int off = 32; off > 0; off >>= 1) mx = fmaxf(mx, __shfl_xor(mx, off, 64));
    const float e0 = expf(x0 - mx), e1 = expf(x1 - mx);
    float s = e0 + e1;
#pragma unroll
    for (int off = 32; off > 0; off >>= 1) s += __shfl_xor(s, off, 64);
    const float f0 = e0 / s, f1 = e1 / s;
    const int o = obs[b];
    const float ep0 = ((lane == o) ? 1.f : 0.f) - f0;
    const float ep1 = ((lane + 64 == o) ? 1.f : 0.f) - f1;
    float d = f0 * ep0 + f1 * ep1;
#pragma unroll
    for (int off = 32; off > 0; off >>= 1) d += __shfl_xor(d, off, 64);
    Jv[(size_t)b * NOBS + lane]      = f0 * (ep0 - d);
    Jv[(size_t)b * NOBS + lane + 64] = f1 * (ep1 - d);
}

// final softmax -> output probabilities
__global__ __launch_bounds__(256)
void softmax_out_k(const float* __restrict__ L, float* __restrict__ out)
{
    const int wid = threadIdx.x >> 6, lane = threadIdx.x & 63;
    const int b = blockIdx.x * 4 + wid;
    const float* lp = L + (size_t)b * NOBS;
    const float x0 = lp[lane], x1 = lp[lane + 64];
    float mx = fmaxf(x0, x1);
#pragma unroll
    for (int off = 32; off > 0; off >>= 1) mx = fmaxf(mx, __shfl_xor(mx, off, 64));
    const float e0 = expf(x0 - mx), e1 = expf(x1 - mx);
    float s = e0 + e1;
#pragma unroll
    for (int off = 32; off > 0; off >>= 1) s += __shfl_xor(s, off, 64);
    out[(size_t)b * NOBS + lane]      = e0 / s;
    out[(size_t)b * NOBS + lane + 64] = e1 / s;
}

// stage-1 of mean(prev - cur): per-block double partials (deterministic)
__global__ __launch_bounds__(256)
void cond_part_k(const float* __restrict__ P, const float* __restrict__ C,
                 double* __restrict__ partials, const int* __restrict__ done)
{
    if (*done) return;
    __shared__ double wsum[4];
    double s = 0.0;
    for (size_t i = (size_t)blockIdx.x * 256 + threadIdx.x; i < (size_t)B_ * H_;
         i += (size_t)2048 * 256)
        s += (double)P[i] - (double)C[i];
#pragma unroll
    for (int off = 32; off > 0; off >>= 1) s += __shfl_down(s, off, 64);
    const int lane = threadIdx.x & 63, wid = threadIdx.x >> 6;
    if (lane == 0) wsum[wid] = s;
    __syncthreads();
    if (threadIdx.x == 0) partials[blockIdx.x] = wsum[0] + wsum[1] + wsum[2] + wsum[3];
}

// stage-2: finalize cond, set active/done (replicates scan gating exactly)
__global__ __launch_bounds__(256)
void cond_fin_k(const double* __restrict__ partials, int* active, int* done)
{
    if (*done) { if (threadIdx.x == 0) *active = 0; return; }
    __shared__ double wsum[4];
    double s = 0.0;
    for (int i = threadIdx.x; i < 2048; i += 256) s += partials[i];
#pragma unroll
    for (int off = 32; off > 0; off >>= 1) s += __shfl_down(s, off, 64);
    const int lane = threadIdx.x & 63, wid = threadIdx.x >> 6;
    if (lane == 0) wsum[wid] = s;
    __syncthreads();
    if (threadIdx.x == 0) {
        const double mean = (wsum[0] + wsum[1] + wsum[2] + wsum[3]) / (double)((size_t)B_ * H_);
        const int c = (fabs(mean) > TOLC) ? 1 : 0;
        *active = c;
        if (!c) *done = 1;
    }
}

// P = C (only when active). cur itself is replaced by the gated rownorm.
__global__ __launch_bounds__(256)
void adv_k(const float* __restrict__ C, float* __restrict__ P, const int* __restrict__ active)
{
    if (*active == 0) return;
    const size_t i = (size_t)blockIdx.x * 256 + threadIdx.x;
    ((float4*)P)[i] = ((const float4*)C)[i];
}

__global__ __launch_bounds__(256)
void copy_k(const float* __restrict__ src, float* __restrict__ dst)
{
    const size_t i = (size_t)blockIdx.x * 256 + threadIdx.x;
    ((float4*)dst)[i] = ((const float4*)src)[i];
}

__global__ void flags_init_k(int* flags) { flags[0] = 0; flags[1] = 0; }

// ---------------------------------------------------------------------------
extern "C" void kernel_launch(void* const* d_in, const int* in_sizes, int n_in,
                              void* d_out, int out_size, void* d_ws, size_t ws_size,
                              hipStream_t stream)
{
    const int*   dirs  = (const int*)d_in[0];
    const int*   obs   = (const int*)d_in[1];
    const float* Wr    = (const float*)d_in[2];
    const float* Win   = (const float*)d_in[3];
    const float* Wout  = (const float*)d_in[4];
    const float* prev0 = (const float*)d_in[5];
    float* out = (float*)d_out;

    const size_t SZ = (size_t)B_ * H_;
    float* P  = (float*)d_ws;
    float* C  = P + SZ;
    float* T  = C + SZ;
    float* L  = T + SZ;
    float* Jv = L + (size_t)B_ * NOBS;
    double* partials = (double*)(Jv + (size_t)B_ * NOBS);
    int* flags  = (int*)(partials + 2048);
    int* done   = flags;
    int* active = flags + 1;

    const dim3 blk(256);

    flags_init_k<<<1, 1, 0, stream>>>(flags);

    // initial cur = norm(relu(Wr @ prev0 + drive))  (reads prev0 input directly)
    gemm_k<128, 128, 16, 8, 8, 1, 1><<<dim3(H_ / 128, B_ / 128), blk, 0, stream>>>(
        prev0, H_, Wr, H_, T, H_, H_, dirs, Win, nullptr, nullptr, nullptr);
    rownorm_k<<<B_, blk, 0, stream>>>(T, C, nullptr);

    for (int it = 0; it < MAXIT; ++it) {
        const float* Pin = (it == 0) ? prev0 : P;  // iter0 prev is the input

        cond_part_k<<<2048, blk, 0, stream>>>(Pin, C, partials, done);
        cond_fin_k<<<1, blk, 0, stream>>>(partials, active, done);

        // R = relu(Wr @ prev + drive)  -> T
        gemm_k<128, 128, 16, 8, 8, 1, 1><<<dim3(H_ / 128, B_ / 128), blk, 0, stream>>>(
            Pin, H_, Wr, H_, T, H_, H_, dirs, Win, nullptr, nullptr, active);
        // logits = cur @ Wout^T -> L
        gemm_k<128, 32, 32, 4, 4, 1, 0><<<dim3(NOBS / 32, B_ / 128), blk, 0, stream>>>(
            C, H_, Wout, H_, L, NOBS, H_, nullptr, nullptr, nullptr, nullptr, active);
        softmax_jv_k<<<B_ / 4, blk, 0, stream>>>(L, obs, Jv, active);
        // T = cur + lr*((R - cur) + Jv @ Wout)   (Rin aliases O=T, per-element safe)
        gemm_k<128, 128, 16, 8, 8, 0, 3><<<dim3(H_ / 128, B_ / 128), blk, 0, stream>>>(
            Jv, NOBS, Wout, H_, T, H_, NOBS, nullptr, nullptr, C, T, active);
        // prev = cur (gated), then cur = norm(T) (gated)
        adv_k<<<SZ / 4 / 256, blk, 0, stream>>>(C, P, active);
        rownorm_k<<<B_, blk, 0, stream>>>(T, C, active);
    }

    // outputs: softmax(Wout @ cur) then cur
    gemm_k<128, 32, 32, 4, 4, 1, 0><<<dim3(NOBS / 32, B_ / 128), blk, 0, stream>>>(
        C, H_, Wout, H_, L, NOBS, H_, nullptr, nullptr, nullptr, nullptr, nullptr);
    softmax_out_k<<<B_ / 4, blk, 0, stream>>>(L, out);
    copy_k<<<SZ / 4 / 256, blk, 0, stream>>>(C, out + (size_t)B_ * NOBS);
}

// Round 2
// 581.520 us; speedup vs baseline: 1.3308x; 1.3308x over previous
//
#include <hip/hip_runtime.h>
#include <cstdint>
#include <cstddef>

#define B_    4096
#define H_    1024
#define NOBS  128
#define NDIR  64
#define MAXIT 10
#define LRI   1e-3f
#define TOLC  1e-3

typedef __bf16 bf16x8 __attribute__((ext_vector_type(8)));
typedef float  f32x4  __attribute__((ext_vector_type(4)));

__device__ __forceinline__ ushort f2bf(float x) {
    uint32_t u = __float_as_uint(x);
    u += 0x7FFFu + ((u >> 16) & 1u);   // RN-even to bf16
    return (ushort)(u >> 16);
}
__device__ __forceinline__ float bf2f(ushort h) {
    return __uint_as_float(((uint32_t)h) << 16);
}

// ---------------------------------------------------------------------------
// fp32 -> (hi, lo) bf16 split. n4 = elems/4 blocks of 256.
// ---------------------------------------------------------------------------
__global__ __launch_bounds__(256)
void split_k(const float* __restrict__ x, ushort* __restrict__ hi,
             ushort* __restrict__ lo)
{
    const size_t i = (size_t)blockIdx.x * 256 + threadIdx.x;
    const float4 v = ((const float4*)x)[i];
    ushort4 h, l;
    h.x = f2bf(v.x); l.x = f2bf(v.x - bf2f(h.x));
    h.y = f2bf(v.y); l.y = f2bf(v.y - bf2f(h.y));
    h.z = f2bf(v.z); l.z = f2bf(v.z - bf2f(h.z));
    h.w = f2bf(v.w); l.w = f2bf(v.w - bf2f(h.w));
    ((ushort4*)hi)[i] = h;
    ((ushort4*)lo)[i] = l;
}

// ---------------------------------------------------------------------------
// Big GEMM on matrix cores, bf16x3 fp32 emulation.
//   O[m,n] = relu( sum_k A[m,k]*Bt[n,k] + Win[n, dirs[m]] )
// A = prev split (hi/lo bf16, [B_][H_]), Bt = Wr split ([H_][H_], row = n).
// 128x128 tile, BK=32, 4 waves (2x2), each wave 4x4 frags of 16x16x32.
// LDS linear-dest global_load_lds + pre-swizzled global source; ds_read uses
// slot = kb ^ ((row>>1)&3) so 16-lane row sweeps cover all 8 128B-wraps.
// ---------------------------------------------------------------------------
__global__ __launch_bounds__(256)
void mfma_gemm_k(const ushort* __restrict__ Ahi, const ushort* __restrict__ Alo,
                 const ushort* __restrict__ Bhi, const ushort* __restrict__ Blo,
                 float* __restrict__ O,
                 const int* __restrict__ dirs, const float* __restrict__ Win,
                 const int* gate)
{
    if (gate && *gate == 0) return;

    __shared__ ushort sAhi[128 * 32];
    __shared__ ushort sAlo[128 * 32];
    __shared__ ushort sBhi[128 * 32];
    __shared__ ushort sBlo[128 * 32];

    const int tid  = threadIdx.x;
    const int lane = tid & 63;
    const int wid  = tid >> 6;
    const int m0 = blockIdx.y * 128;
    const int n0 = blockIdx.x * 128;
    const int wr = wid >> 1, wc = wid & 1;

    f32x4 acc[4][4];
#pragma unroll
    for (int i = 0; i < 4; ++i)
#pragma unroll
        for (int j = 0; j < 4; ++j) acc[i][j] = (f32x4){0.f, 0.f, 0.f, 0.f};

    const int rsel = lane & 15;
    const int kb   = lane >> 4;

#define STAGE4(dstA, srcA, rowbase)                                            \
    {                                                                          \
        _Pragma("unroll")                                                      \
        for (int cc = 0; cc < 2; ++cc) {                                       \
            const int c = cc * 256 + tid;                                      \
            const int r = c >> 2, s = c & 3;                                   \
            const int ks = ((s ^ ((r >> 1) & 3)) << 3);                        \
            const ushort* g = srcA + (size_t)(rowbase + r) * H_ + k0 + ks;     \
            __builtin_amdgcn_global_load_lds(                                  \
                (const __attribute__((address_space(1))) void*)g,              \
                (__attribute__((address_space(3))) void*)(dstA +               \
                    (cc * 256 + wid * 64) * 8),                                \
                16, 0, 0);                                                     \
        }                                                                      \
    }

    for (int k0 = 0; k0 < H_; k0 += 32) {
        STAGE4(sAhi, Ahi, m0);
        STAGE4(sAlo, Alo, m0);
        STAGE4(sBhi, Bhi, n0);
        STAGE4(sBlo, Blo, n0);
        __syncthreads();   // compiler emits vmcnt(0) drain before barrier

        bf16x8 ah[4], al[4], bh[4], bl[4];
#pragma unroll
        for (int f = 0; f < 4; ++f) {
            const int arow = wr * 64 + f * 16 + rsel;
            const int aoff = arow * 32 + ((kb ^ ((arow >> 1) & 3)) << 3);
            ah[f] = *(const bf16x8*)&sAhi[aoff];
            al[f] = *(const bf16x8*)&sAlo[aoff];
            const int brow = wc * 64 + f * 16 + rsel;
            const int boff = brow * 32 + ((kb ^ ((brow >> 1) & 3)) << 3);
            bh[f] = *(const bf16x8*)&sBhi[boff];
            bl[f] = *(const bf16x8*)&sBlo[boff];
        }

#pragma unroll
        for (int i = 0; i < 4; ++i)
#pragma unroll
            for (int j = 0; j < 4; ++j) {
                acc[i][j] = __builtin_amdgcn_mfma_f32_16x16x32_bf16(
                    ah[i], bh[j], acc[i][j], 0, 0, 0);
                acc[i][j] = __builtin_amdgcn_mfma_f32_16x16x32_bf16(
                    ah[i], bl[j], acc[i][j], 0, 0, 0);
                acc[i][j] = __builtin_amdgcn_mfma_f32_16x16x32_bf16(
                    al[i], bh[j], acc[i][j], 0, 0, 0);
            }
        __syncthreads();
    }
#undef STAGE4

    // epilogue: relu(acc + drive), C/D layout col=lane&15, row=(lane>>4)*4+r
#pragma unroll
    for (int i = 0; i < 4; ++i) {
#pragma unroll
        for (int r = 0; r < 4; ++r) {
            const int row = m0 + wr * 64 + i * 16 + (lane >> 4) * 4 + r;
            const int dd  = dirs[row];
#pragma unroll
            for (int j = 0; j < 4; ++j) {
                const int col = n0 + wc * 64 + j * 16 + (lane & 15);
                const float v = acc[i][j][r] + Win[(size_t)col * NDIR + dd];
                O[(size_t)row * H_ + col] = fmaxf(v, 0.f);
            }
        }
    }
}

// ---------------------------------------------------------------------------
// fp32 tiled GEMM (kept for the two thin Wout products):
//   WT=1: O[m,n] = sum_k W[n*ldW + k] * S[m*ldS + k]
//   WT=0: O[m,n] = sum_k W[k*ldW + n] * S[m*ldS + k]
// EPI=0: store acc ; EPI=3: store Cin + LRI*((Rin - Cin) + acc)
// ---------------------------------------------------------------------------
template<int BM, int BN, int BK, int TM, int TN, int WT, int EPI>
__global__ __launch_bounds__(256)
void gemm_k(const float* __restrict__ S, int ldS,
            const float* __restrict__ W, int ldW,
            float* O, int ldO, int K,
            const float* Cin, const float* Rin,
            const int* gate)
{
    if (gate && *gate == 0) return;

    __shared__ float sS[BK][BM + 4];
    __shared__ float sW[BK][BN + 4];

    const int tid = threadIdx.x;
    const int m0 = blockIdx.y * BM;
    const int n0 = blockIdx.x * BN;
    constexpr int NTC = BN / TN;
    const int tr = tid / NTC;
    const int tc = tid % NTC;

    float acc[TM][TN];
#pragma unroll
    for (int i = 0; i < TM; ++i)
#pragma unroll
        for (int j = 0; j < TN; ++j) acc[i][j] = 0.f;

    for (int k0 = 0; k0 < K; k0 += BK) {
#pragma unroll
        for (int t = tid; t < BM * BK / 4; t += 256) {
            const int r  = t / (BK / 4);
            const int c4 = (t % (BK / 4)) * 4;
            const float4 v = *(const float4*)(S + (size_t)(m0 + r) * ldS + k0 + c4);
            sS[c4 + 0][r] = v.x; sS[c4 + 1][r] = v.y;
            sS[c4 + 2][r] = v.z; sS[c4 + 3][r] = v.w;
        }
        if (WT) {
#pragma unroll
            for (int t = tid; t < BN * BK / 4; t += 256) {
                const int r  = t / (BK / 4);
                const int c4 = (t % (BK / 4)) * 4;
                const float4 v = *(const float4*)(W + (size_t)(n0 + r) * ldW + k0 + c4);
                sW[c4 + 0][r] = v.x; sW[c4 + 1][r] = v.y;
                sW[c4 + 2][r] = v.z; sW[c4 + 3][r] = v.w;
            }
        } else {
#pragma unroll
            for (int t = tid; t < BK * BN / 4; t += 256) {
                const int r  = t / (BN / 4);
                const int c4 = (t % (BN / 4)) * 4;
                *(float4*)(&sW[r][c4]) =
                    *(const float4*)(W + (size_t)(k0 + r) * ldW + n0 + c4);
            }
        }
        __syncthreads();

#pragma unroll
        for (int k = 0; k < BK; ++k) {
            float a[TM], b[TN];
#pragma unroll
            for (int i = 0; i < TM; i += 4) {
                const float4 v = *(const float4*)(&sS[k][tr * TM + i]);
                a[i] = v.x; a[i + 1] = v.y; a[i + 2] = v.z; a[i + 3] = v.w;
            }
#pragma unroll
            for (int j = 0; j < TN; j += 4) {
                const float4 v = *(const float4*)(&sW[k][tc * TN + j]);
                b[j] = v.x; b[j + 1] = v.y; b[j + 2] = v.z; b[j + 3] = v.w;
            }
#pragma unroll
            for (int i = 0; i < TM; ++i)
#pragma unroll
                for (int j = 0; j < TN; ++j)
                    acc[i][j] = fmaf(a[i], b[j], acc[i][j]);
        }
        __syncthreads();
    }

#pragma unroll
    for (int i = 0; i < TM; ++i) {
        const int m = m0 + tr * TM + i;
#pragma unroll
        for (int j = 0; j < TN; j += 4) {
            const int n = n0 + tc * TN + j;
            const size_t idx = (size_t)m * ldO + n;
            float4 v;
            v.x = acc[i][j]; v.y = acc[i][j + 1]; v.z = acc[i][j + 2]; v.w = acc[i][j + 3];
            if (EPI == 3) {
                const float4 cv = *(const float4*)(Cin + idx);
                const float4 rv = *(const float4*)(Rin + idx);
                v.x = cv.x + LRI * ((rv.x - cv.x) + v.x);
                v.y = cv.y + LRI * ((rv.y - cv.y) + v.y);
                v.z = cv.z + LRI * ((rv.z - cv.z) + v.z);
                v.w = cv.w + LRI * ((rv.w - cv.w) + v.w);
            }
            *(float4*)(O + idx) = v;
        }
    }
}

// row-wise L2 normalize: Cout[b,:] = T[b,:] / (||T[b,:]|| + 1e-6)
__global__ __launch_bounds__(256)
void rownorm_k(const float* __restrict__ T, float* __restrict__ Cout, const int* gate)
{
    if (gate && *gate == 0) return;
    __shared__ float wsum[4];
    const int b = blockIdx.x;
    const float4 v = ((const float4*)(T + (size_t)b * H_))[threadIdx.x];
    float ss = v.x * v.x + v.y * v.y + v.z * v.z + v.w * v.w;
#pragma unroll
    for (int off = 32; off > 0; off >>= 1) ss += __shfl_down(ss, off, 64);
    const int lane = threadIdx.x & 63, wid = threadIdx.x >> 6;
    if (lane == 0) wsum[wid] = ss;
    __syncthreads();
    const float tot = wsum[0] + wsum[1] + wsum[2] + wsum[3];
    const float d = sqrtf(tot) + 1e-6f;
    float4 o;
    o.x = v.x / d; o.y = v.y / d; o.z = v.z / d; o.w = v.w / d;
    ((float4*)(Cout + (size_t)b * H_))[threadIdx.x] = o;
}

// softmax over 128 logits + softmax-Jacobian vector product. 1 wave = 1 row.
__global__ __launch_bounds__(256)
void softmax_jv_k(const float* __restrict__ L, const int* __restrict__ obs,
                  float* __restrict__ Jv, const int* gate)
{
    if (gate && *gate == 0) return;
    const int wid = threadIdx.x >> 6, lane = threadIdx.x & 63;
    const int b = blockIdx.x * 4 + wid;
    const float* lp = L + (size_t)b * NOBS;
    const float x0 = lp[lane], x1 = lp[lane + 64];
    float mx = fmaxf(x0, x1);
#pragma unroll
    for (int off = 32; off > 0; off >>= 1) mx = fmaxf(mx, __shfl_xor(mx, off, 64));
    const float e0 = expf(x0 - mx), e1 = expf(x1 - mx);
    float s = e0 + e1;
#pragma unroll
    for (int off = 32; off > 0; off >>= 1) s += __shfl_xor(s, off, 64);
    const float f0 = e0 / s, f1 = e1 / s;
    const int o = obs[b];
    const float ep0 = ((lane == o) ? 1.f : 0.f) - f0;
    const float ep1 = ((lane + 64 == o) ? 1.f : 0.f) - f1;
    float d = f0 * ep0 + f1 * ep1;
#pragma unroll
    for (int off = 32; off > 0; off >>= 1) d += __shfl_xor(d, off, 64);
    Jv[(size_t)b * NOBS + lane]      = f0 * (ep0 - d);
    Jv[(size_t)b * NOBS + lane + 64] = f1 * (ep1 - d);
}

// final softmax -> output probabilities
__global__ __launch_bounds__(256)
void softmax_out_k(const float* __restrict__ L, float* __restrict__ out)
{
    const int wid = threadIdx.x >> 6, lane = threadIdx.x & 63;
    const int b = blockIdx.x * 4 + wid;
    const float* lp = L + (size_t)b * NOBS;
    const float x0 = lp[lane], x1 = lp[lane + 64];
    float mx = fmaxf(x0, x1);
#pragma unroll
    for (int off = 32; off > 0; off >>= 1) mx = fmaxf(mx, __shfl_xor(mx, off, 64));
    const float e0 = expf(x0 - mx), e1 = expf(x1 - mx);
    float s = e0 + e1;
#pragma unroll
    for (int off = 32; off > 0; off >>= 1) s += __shfl_xor(s, off, 64);
    out[(size_t)b * NOBS + lane]      = e0 / s;
    out[(size_t)b * NOBS + lane + 64] = e1 / s;
}

// stage-1 of mean(prev - cur): per-block double partials (deterministic)
__global__ __launch_bounds__(256)
void cond_part_k(const float* __restrict__ P, const float* __restrict__ C,
                 double* __restrict__ partials, const int* __restrict__ done)
{
    if (*done) return;
    __shared__ double wsum[4];
    double s = 0.0;
    for (size_t i = (size_t)blockIdx.x * 256 + threadIdx.x; i < (size_t)B_ * H_;
         i += (size_t)2048 * 256)
        s += (double)P[i] - (double)C[i];
#pragma unroll
    for (int off = 32; off > 0; off >>= 1) s += __shfl_down(s, off, 64);
    const int lane = threadIdx.x & 63, wid = threadIdx.x >> 6;
    if (lane == 0) wsum[wid] = s;
    __syncthreads();
    if (threadIdx.x == 0) partials[blockIdx.x] = wsum[0] + wsum[1] + wsum[2] + wsum[3];
}

// stage-2: finalize cond, set active/done (replicates scan gating exactly)
__global__ __launch_bounds__(256)
void cond_fin_k(const double* __restrict__ partials, int* active, int* done)
{
    if (*done) { if (threadIdx.x == 0) *active = 0; return; }
    __shared__ double wsum[4];
    double s = 0.0;
    for (int i = threadIdx.x; i < 2048; i += 256) s += partials[i];
#pragma unroll
    for (int off = 32; off > 0; off >>= 1) s += __shfl_down(s, off, 64);
    const int lane = threadIdx.x & 63, wid = threadIdx.x >> 6;
    if (lane == 0) wsum[wid] = s;
    __syncthreads();
    if (threadIdx.x == 0) {
        const double mean = (wsum[0] + wsum[1] + wsum[2] + wsum[3]) / (double)((size_t)B_ * H_);
        const int c = (fabs(mean) > TOLC) ? 1 : 0;
        *active = c;
        if (!c) *done = 1;
    }
}

// P = C and (Phi,Plo) = split(C), only when active.
__global__ __launch_bounds__(256)
void adv_split_k(const float* __restrict__ C, float* __restrict__ P,
                 ushort* __restrict__ Phi, ushort* __restrict__ Plo,
                 const int* __restrict__ active)
{
    if (*active == 0) return;
    const size_t i = (size_t)blockIdx.x * 256 + threadIdx.x;
    const float4 v = ((const float4*)C)[i];
    ((float4*)P)[i] = v;
    ushort4 h, l;
    h.x = f2bf(v.x); l.x = f2bf(v.x - bf2f(h.x));
    h.y = f2bf(v.y); l.y = f2bf(v.y - bf2f(h.y));
    h.z = f2bf(v.z); l.z = f2bf(v.z - bf2f(h.z));
    h.w = f2bf(v.w); l.w = f2bf(v.w - bf2f(h.w));
    ((ushort4*)Phi)[i] = h;
    ((ushort4*)Plo)[i] = l;
}

__global__ __launch_bounds__(256)
void copy_k(const float* __restrict__ src, float* __restrict__ dst)
{
    const size_t i = (size_t)blockIdx.x * 256 + threadIdx.x;
    ((float4*)dst)[i] = ((const float4*)src)[i];
}

__global__ void flags_init_k(int* flags) { flags[0] = 0; flags[1] = 0; }

// ---------------------------------------------------------------------------
extern "C" void kernel_launch(void* const* d_in, const int* in_sizes, int n_in,
                              void* d_out, int out_size, void* d_ws, size_t ws_size,
                              hipStream_t stream)
{
    const int*   dirs  = (const int*)d_in[0];
    const int*   obs   = (const int*)d_in[1];
    const float* Wr    = (const float*)d_in[2];
    const float* Win   = (const float*)d_in[3];
    const float* Wout  = (const float*)d_in[4];
    const float* prev0 = (const float*)d_in[5];
    float* out = (float*)d_out;

    const size_t SZ = (size_t)B_ * H_;
    float* P  = (float*)d_ws;
    float* C  = P + SZ;
    float* T  = C + SZ;
    float* L  = T + SZ;
    float* Jv = L + (size_t)B_ * NOBS;
    double* partials = (double*)(Jv + (size_t)B_ * NOBS);
    int* flags  = (int*)(partials + 2048);
    int* done   = flags;
    int* active = flags + 1;
    ushort* Phi  = (ushort*)(flags + 16);
    ushort* Plo  = Phi + SZ;
    ushort* Wrhi = Plo + SZ;
    ushort* Wrlo = Wrhi + (size_t)H_ * H_;

    const dim3 blk(256);

    flags_init_k<<<1, 1, 0, stream>>>(flags);
    split_k<<<(H_ * H_ / 4) / 256, blk, 0, stream>>>(Wr, Wrhi, Wrlo);
    split_k<<<(B_ * H_ / 4) / 256, blk, 0, stream>>>(prev0, Phi, Plo);

    // initial cur = norm(relu(Wr @ prev0 + drive))
    mfma_gemm_k<<<dim3(H_ / 128, B_ / 128), blk, 0, stream>>>(
        Phi, Plo, Wrhi, Wrlo, T, dirs, Win, nullptr);
    rownorm_k<<<B_, blk, 0, stream>>>(T, C, nullptr);

    for (int it = 0; it < MAXIT; ++it) {
        const float* Pin = (it == 0) ? prev0 : P;

        cond_part_k<<<2048, blk, 0, stream>>>(Pin, C, partials, done);
        cond_fin_k<<<1, blk, 0, stream>>>(partials, active, done);

        // R = relu(Wr @ prev + drive) -> T   (MFMA bf16x3; Phi/Plo == split(Pin))
        mfma_gemm_k<<<dim3(H_ / 128, B_ / 128), blk, 0, stream>>>(
            Phi, Plo, Wrhi, Wrlo, T, dirs, Win, active);
        // logits = cur @ Wout^T -> L
        gemm_k<128, 32, 32, 4, 4, 1, 0><<<dim3(NOBS / 32, B_ / 128), blk, 0, stream>>>(
            C, H_, Wout, H_, L, NOBS, H_, nullptr, nullptr, active);
        softmax_jv_k<<<B_ / 4, blk, 0, stream>>>(L, obs, Jv, active);
        // T = cur + lr*((R - cur) + Jv @ Wout)
        gemm_k<128, 128, 16, 8, 8, 0, 3><<<dim3(H_ / 128, B_ / 128), blk, 0, stream>>>(
            Jv, NOBS, Wout, H_, T, H_, NOBS, C, T, active);
        // prev = cur (+ bf16 split for next GEMM), then cur = norm(T)
        adv_split_k<<<SZ / 4 / 256, blk, 0, stream>>>(C, P, Phi, Plo, active);
        rownorm_k<<<B_, blk, 0, stream>>>(T, C, active);
    }

    // outputs: softmax(Wout @ cur) then cur
    gemm_k<128, 32, 32, 4, 4, 1, 0><<<dim3(NOBS / 32, B_ / 128), blk, 0, stream>>>(
        C, H_, Wout, H_, L, NOBS, H_, nullptr, nullptr, nullptr);
    softmax_out_k<<<B_ / 4, blk, 0, stream>>>(L, out);
    copy_k<<<SZ / 4 / 256, blk, 0, stream>>>(C, out + (size_t)B_ * NOBS);
}

// Round 3
// 330.555 us; speedup vs baseline: 2.3412x; 1.7592x over previous
//
#include <hip/hip_runtime.h>
#include <cstdint>
#include <cstddef>

#define B_    4096
#define H_    1024
#define NOBS  128
#define NDIR  64
#define MAXIT 10
#define LRI   1e-3f
#define TOLC  1e-3
#define KS_   8      // split-K factor for logits GEMM

typedef __bf16 bf16x8 __attribute__((ext_vector_type(8)));
typedef float  f32x4  __attribute__((ext_vector_type(4)));

__device__ __forceinline__ ushort f2bf(float x) {
    uint32_t u = __float_as_uint(x);
    u += 0x7FFFu + ((u >> 16) & 1u);   // RN-even to bf16
    return (ushort)(u >> 16);
}
__device__ __forceinline__ float bf2f(ushort h) {
    return __uint_as_float(((uint32_t)h) << 16);
}

// ---------------------------------------------------------------------------
// Stage one 128row x 32col bf16 tile into LDS via global_load_lds (16B/lane),
// with XOR-swizzled global source so the ds_read side is low-conflict.
// ---------------------------------------------------------------------------
__device__ __forceinline__ void stage_tile(ushort* dst, const ushort* src,
                                           size_t rowbase, int ld, int k0,
                                           int tid, int wid)
{
#pragma unroll
    for (int cc = 0; cc < 2; ++cc) {
        const int c = cc * 256 + tid;
        const int r = c >> 2, s = c & 3;
        const int ks = ((s ^ ((r >> 1) & 3)) << 3);
        const ushort* g = src + (rowbase + r) * (size_t)ld + k0 + ks;
        __builtin_amdgcn_global_load_lds(
            (const __attribute__((address_space(1))) void*)g,
            (__attribute__((address_space(3))) void*)(dst + (cc * 256 + wid * 64) * 8),
            16, 0, 0);
    }
}

// ---------------------------------------------------------------------------
// Big GEMM: O = relu(prev @ Wr^T + drive), bf16x3 fp32 emulation on MFMA.
// 128x128 tile, BK=32, 4 waves (2x2), wave = 4x4 frags of 16x16x32.
// ---------------------------------------------------------------------------
__global__ __launch_bounds__(256)
void mfma_gemm_k(const ushort* __restrict__ Ahi, const ushort* __restrict__ Alo,
                 const ushort* __restrict__ Bhi, const ushort* __restrict__ Blo,
                 float* __restrict__ O,
                 const int* __restrict__ dirs, const float* __restrict__ Win,
                 const int* gate)
{
    if (gate && *gate == 0) return;

    __shared__ ushort sAhi[128 * 32];
    __shared__ ushort sAlo[128 * 32];
    __shared__ ushort sBhi[128 * 32];
    __shared__ ushort sBlo[128 * 32];

    const int tid  = threadIdx.x;
    const int lane = tid & 63;
    const int wid  = tid >> 6;
    const int m0 = blockIdx.y * 128;
    const int n0 = blockIdx.x * 128;
    const int wr = wid >> 1, wc = wid & 1;

    f32x4 acc[4][4];
#pragma unroll
    for (int i = 0; i < 4; ++i)
#pragma unroll
        for (int j = 0; j < 4; ++j) acc[i][j] = (f32x4){0.f, 0.f, 0.f, 0.f};

    const int rsel = lane & 15;
    const int kb   = lane >> 4;

    for (int k0 = 0; k0 < H_; k0 += 32) {
        stage_tile(sAhi, Ahi, m0, H_, k0, tid, wid);
        stage_tile(sAlo, Alo, m0, H_, k0, tid, wid);
        stage_tile(sBhi, Bhi, n0, H_, k0, tid, wid);
        stage_tile(sBlo, Blo, n0, H_, k0, tid, wid);
        __syncthreads();

        bf16x8 ah[4], al[4], bh[4], bl[4];
#pragma unroll
        for (int f = 0; f < 4; ++f) {
            const int arow = wr * 64 + f * 16 + rsel;
            const int aoff = arow * 32 + ((kb ^ ((arow >> 1) & 3)) << 3);
            ah[f] = *(const bf16x8*)&sAhi[aoff];
            al[f] = *(const bf16x8*)&sAlo[aoff];
            const int brow = wc * 64 + f * 16 + rsel;
            const int boff = brow * 32 + ((kb ^ ((brow >> 1) & 3)) << 3);
            bh[f] = *(const bf16x8*)&sBhi[boff];
            bl[f] = *(const bf16x8*)&sBlo[boff];
        }

#pragma unroll
        for (int i = 0; i < 4; ++i)
#pragma unroll
            for (int j = 0; j < 4; ++j) {
                acc[i][j] = __builtin_amdgcn_mfma_f32_16x16x32_bf16(ah[i], bh[j], acc[i][j], 0, 0, 0);
                acc[i][j] = __builtin_amdgcn_mfma_f32_16x16x32_bf16(ah[i], bl[j], acc[i][j], 0, 0, 0);
                acc[i][j] = __builtin_amdgcn_mfma_f32_16x16x32_bf16(al[i], bh[j], acc[i][j], 0, 0, 0);
            }
        __syncthreads();
    }

#pragma unroll
    for (int i = 0; i < 4; ++i) {
#pragma unroll
        for (int r = 0; r < 4; ++r) {
            const int row = m0 + wr * 64 + i * 16 + (lane >> 4) * 4 + r;
            const int dd  = dirs[row];
#pragma unroll
            for (int j = 0; j < 4; ++j) {
                const int col = n0 + wc * 64 + j * 16 + (lane & 15);
                const float v = acc[i][j][r] + Win[(size_t)col * NDIR + dd];
                O[(size_t)row * H_ + col] = fmaxf(v, 0.f);
            }
        }
    }
}

// ---------------------------------------------------------------------------
// Split-K logits GEMM: part[kb, m, o] = sum_{k in chunk kb} cur[m,k]*Wout[o,k]
// grid (KS_, B_/128); bf16x3.
// ---------------------------------------------------------------------------
__global__ __launch_bounds__(256)
void logits_mfma_k(const ushort* __restrict__ Ahi, const ushort* __restrict__ Alo,
                   const ushort* __restrict__ Bhi, const ushort* __restrict__ Blo,
                   float* __restrict__ part, const int* gate)
{
    if (gate && *gate == 0) return;

    __shared__ ushort sAhi[128 * 32];
    __shared__ ushort sAlo[128 * 32];
    __shared__ ushort sBhi[128 * 32];
    __shared__ ushort sBlo[128 * 32];

    const int tid  = threadIdx.x;
    const int lane = tid & 63;
    const int wid  = tid >> 6;
    const int m0 = blockIdx.y * 128;
    const int kbase = blockIdx.x * (H_ / KS_);
    const int wr = wid >> 1, wc = wid & 1;

    f32x4 acc[4][4];
#pragma unroll
    for (int i = 0; i < 4; ++i)
#pragma unroll
        for (int j = 0; j < 4; ++j) acc[i][j] = (f32x4){0.f, 0.f, 0.f, 0.f};

    const int rsel = lane & 15;
    const int kb   = lane >> 4;

    for (int kk = 0; kk < H_ / KS_; kk += 32) {
        const int k0 = kbase + kk;
        stage_tile(sAhi, Ahi, m0, H_, k0, tid, wid);
        stage_tile(sAlo, Alo, m0, H_, k0, tid, wid);
        stage_tile(sBhi, Bhi, 0, H_, k0, tid, wid);
        stage_tile(sBlo, Blo, 0, H_, k0, tid, wid);
        __syncthreads();

        bf16x8 ah[4], al[4], bh[4], bl[4];
#pragma unroll
        for (int f = 0; f < 4; ++f) {
            const int arow = wr * 64 + f * 16 + rsel;
            const int aoff = arow * 32 + ((kb ^ ((arow >> 1) & 3)) << 3);
            ah[f] = *(const bf16x8*)&sAhi[aoff];
            al[f] = *(const bf16x8*)&sAlo[aoff];
            const int brow = wc * 64 + f * 16 + rsel;
            const int boff = brow * 32 + ((kb ^ ((brow >> 1) & 3)) << 3);
            bh[f] = *(const bf16x8*)&sBhi[boff];
            bl[f] = *(const bf16x8*)&sBlo[boff];
        }

#pragma unroll
        for (int i = 0; i < 4; ++i)
#pragma unroll
            for (int j = 0; j < 4; ++j) {
                acc[i][j] = __builtin_amdgcn_mfma_f32_16x16x32_bf16(ah[i], bh[j], acc[i][j], 0, 0, 0);
                acc[i][j] = __builtin_amdgcn_mfma_f32_16x16x32_bf16(ah[i], bl[j], acc[i][j], 0, 0, 0);
                acc[i][j] = __builtin_amdgcn_mfma_f32_16x16x32_bf16(al[i], bh[j], acc[i][j], 0, 0, 0);
            }
        __syncthreads();
    }

    float* pout = part + (size_t)blockIdx.x * B_ * NOBS;
#pragma unroll
    for (int i = 0; i < 4; ++i)
#pragma unroll
        for (int r = 0; r < 4; ++r) {
            const int row = m0 + wr * 64 + i * 16 + (lane >> 4) * 4 + r;
#pragma unroll
            for (int j = 0; j < 4; ++j) {
                const int col = wc * 64 + j * 16 + (lane & 15);
                pout[(size_t)row * NOBS + col] = acc[i][j][r];
            }
        }
}

// ---------------------------------------------------------------------------
// epi3: T = C + LRI*((T - C) + Jv @ WoutT), Jv [B,128] bf16 split, WT [H,128].
// grid (H_/128, B_/128), K = NOBS = 128.
// ---------------------------------------------------------------------------
__global__ __launch_bounds__(256)
void epi3_mfma_k(const ushort* __restrict__ Ahi, const ushort* __restrict__ Alo,
                 const ushort* __restrict__ Bhi, const ushort* __restrict__ Blo,
                 const float* __restrict__ C, float* __restrict__ T,
                 const int* gate)
{
    if (gate && *gate == 0) return;

    __shared__ ushort sAhi[128 * 32];
    __shared__ ushort sAlo[128 * 32];
    __shared__ ushort sBhi[128 * 32];
    __shared__ ushort sBlo[128 * 32];

    const int tid  = threadIdx.x;
    const int lane = tid & 63;
    const int wid  = tid >> 6;
    const int m0 = blockIdx.y * 128;
    const int n0 = blockIdx.x * 128;
    const int wr = wid >> 1, wc = wid & 1;

    f32x4 acc[4][4];
#pragma unroll
    for (int i = 0; i < 4; ++i)
#pragma unroll
        for (int j = 0; j < 4; ++j) acc[i][j] = (f32x4){0.f, 0.f, 0.f, 0.f};

    const int rsel = lane & 15;
    const int kb   = lane >> 4;

    for (int k0 = 0; k0 < NOBS; k0 += 32) {
        stage_tile(sAhi, Ahi, m0, NOBS, k0, tid, wid);
        stage_tile(sAlo, Alo, m0, NOBS, k0, tid, wid);
        stage_tile(sBhi, Bhi, n0, NOBS, k0, tid, wid);
        stage_tile(sBlo, Blo, n0, NOBS, k0, tid, wid);
        __syncthreads();

        bf16x8 ah[4], al[4], bh[4], bl[4];
#pragma unroll
        for (int f = 0; f < 4; ++f) {
            const int arow = wr * 64 + f * 16 + rsel;
            const int aoff = arow * 32 + ((kb ^ ((arow >> 1) & 3)) << 3);
            ah[f] = *(const bf16x8*)&sAhi[aoff];
            al[f] = *(const bf16x8*)&sAlo[aoff];
            const int brow = wc * 64 + f * 16 + rsel;
            const int boff = brow * 32 + ((kb ^ ((brow >> 1) & 3)) << 3);
            bh[f] = *(const bf16x8*)&sBhi[boff];
            bl[f] = *(const bf16x8*)&sBlo[boff];
        }

#pragma unroll
        for (int i = 0; i < 4; ++i)
#pragma unroll
            for (int j = 0; j < 4; ++j) {
                acc[i][j] = __builtin_amdgcn_mfma_f32_16x16x32_bf16(ah[i], bh[j], acc[i][j], 0, 0, 0);
                acc[i][j] = __builtin_amdgcn_mfma_f32_16x16x32_bf16(ah[i], bl[j], acc[i][j], 0, 0, 0);
                acc[i][j] = __builtin_amdgcn_mfma_f32_16x16x32_bf16(al[i], bh[j], acc[i][j], 0, 0, 0);
            }
        __syncthreads();
    }

#pragma unroll
    for (int i = 0; i < 4; ++i)
#pragma unroll
        for (int r = 0; r < 4; ++r) {
            const int row = m0 + wr * 64 + i * 16 + (lane >> 4) * 4 + r;
#pragma unroll
            for (int j = 0; j < 4; ++j) {
                const int col = n0 + wc * 64 + j * 16 + (lane & 15);
                const size_t idx = (size_t)row * H_ + col;
                const float c = C[idx], rv = T[idx];
                T[idx] = c + LRI * ((rv - c) + acc[i][j][r]);
            }
        }
}

// ---------------------------------------------------------------------------
// Reduce split-K partials -> logits; softmax.
// MODE 0: + Jacobian-vector product, write Jv bf16 split (gated).
// MODE 1: write probabilities to out (ungated, final).
// ---------------------------------------------------------------------------
template<int MODE>
__global__ __launch_bounds__(256)
void softjv_k(const float* __restrict__ part, const int* __restrict__ obs,
              ushort* __restrict__ Jhi, ushort* __restrict__ Jlo,
              float* __restrict__ probs, const int* gate)
{
    if (MODE == 0 && gate && *gate == 0) return;
    const int wid = threadIdx.x >> 6, lane = threadIdx.x & 63;
    const int b = blockIdx.x * 4 + wid;
    float x0 = 0.f, x1 = 0.f;
#pragma unroll
    for (int kb = 0; kb < KS_; ++kb) {
        const float* p = part + ((size_t)kb * B_ + b) * NOBS;
        x0 += p[lane]; x1 += p[lane + 64];
    }
    float mx = fmaxf(x0, x1);
#pragma unroll
    for (int off = 32; off > 0; off >>= 1) mx = fmaxf(mx, __shfl_xor(mx, off, 64));
    const float e0 = expf(x0 - mx), e1 = expf(x1 - mx);
    float s = e0 + e1;
#pragma unroll
    for (int off = 32; off > 0; off >>= 1) s += __shfl_xor(s, off, 64);
    const float f0 = e0 / s, f1 = e1 / s;
    if (MODE == 1) {
        probs[(size_t)b * NOBS + lane]      = f0;
        probs[(size_t)b * NOBS + lane + 64] = f1;
        return;
    }
    const int o = obs[b];
    const float ep0 = ((lane == o) ? 1.f : 0.f) - f0;
    const float ep1 = ((lane + 64 == o) ? 1.f : 0.f) - f1;
    float d = f0 * ep0 + f1 * ep1;
#pragma unroll
    for (int off = 32; off > 0; off >>= 1) d += __shfl_xor(d, off, 64);
    const float j0 = f0 * (ep0 - d), j1 = f1 * (ep1 - d);
    const ushort h0 = f2bf(j0), h1 = f2bf(j1);
    Jhi[(size_t)b * NOBS + lane]      = h0;
    Jlo[(size_t)b * NOBS + lane]      = f2bf(j0 - bf2f(h0));
    Jhi[(size_t)b * NOBS + lane + 64] = h1;
    Jlo[(size_t)b * NOBS + lane + 64] = f2bf(j1 - bf2f(h1));
}

// ---------------------------------------------------------------------------
// Fused advance + row-normalize:
//   if ADV: (Phi,Plo) <- (Chi,Clo)        [prev_{t+1} = cur_t, split copy]
//   C <- norm(T); (Chi,Clo) <- split(C)
//   rowpart[b] <- oldsum[b] - sum(Cnew row); rowsum[b] <- sum(Cnew row)
// ---------------------------------------------------------------------------
template<bool ADV>
__global__ __launch_bounds__(256)
void normadv_k(const float* __restrict__ T, float* __restrict__ C,
               ushort* __restrict__ Chi, ushort* __restrict__ Clo,
               ushort* __restrict__ Phi, ushort* __restrict__ Plo,
               const float* __restrict__ oldsum, float* __restrict__ rowsum,
               double* __restrict__ rowpart, const int* gate)
{
    if (gate && *gate == 0) return;
    const int b = blockIdx.x, tid = threadIdx.x;
    const size_t ro = (size_t)b * H_;

    if (ADV) {
        ((ushort4*)(Phi + ro))[tid] = ((const ushort4*)(Chi + ro))[tid];
        ((ushort4*)(Plo + ro))[tid] = ((const ushort4*)(Clo + ro))[tid];
    }

    const float4 v = ((const float4*)(T + ro))[tid];
    float ss = v.x * v.x + v.y * v.y + v.z * v.z + v.w * v.w;
    float sm = v.x + v.y + v.z + v.w;
#pragma unroll
    for (int off = 32; off > 0; off >>= 1) {
        ss += __shfl_down(ss, off, 64);
        sm += __shfl_down(sm, off, 64);
    }
    __shared__ float w1[4], w2[4];
    const int lane = tid & 63, wid = tid >> 6;
    if (lane == 0) { w1[wid] = ss; w2[wid] = sm; }
    __syncthreads();
    const float tot = w1[0] + w1[1] + w1[2] + w1[3];
    const float smt = w2[0] + w2[1] + w2[2] + w2[3];
    const float d = sqrtf(tot) + 1e-6f;

    float4 o;
    o.x = v.x / d; o.y = v.y / d; o.z = v.z / d; o.w = v.w / d;
    ((float4*)(C + ro))[tid] = o;
    ushort4 h, l;
    h.x = f2bf(o.x); l.x = f2bf(o.x - bf2f(h.x));
    h.y = f2bf(o.y); l.y = f2bf(o.y - bf2f(h.y));
    h.z = f2bf(o.z); l.z = f2bf(o.z - bf2f(h.z));
    h.w = f2bf(o.w); l.w = f2bf(o.w - bf2f(h.w));
    ((ushort4*)(Chi + ro))[tid] = h;
    ((ushort4*)(Clo + ro))[tid] = l;

    if (tid == 0) {
        const float news = smt / d;
        rowpart[b] = (double)oldsum[b] - (double)news;
        rowsum[b]  = news;
    }
}

// finalize cond: reduce 4096 row partials, set active/done (sticky)
__global__ __launch_bounds__(256)
void cond_fin_k(const double* __restrict__ rowpart, int* active, int* done)
{
    if (*done) { if (threadIdx.x == 0) *active = 0; return; }
    __shared__ double wsum[4];
    double s = 0.0;
    for (int i = threadIdx.x; i < B_; i += 256) s += rowpart[i];
#pragma unroll
    for (int off = 32; off > 0; off >>= 1) s += __shfl_down(s, off, 64);
    const int lane = threadIdx.x & 63, wid = threadIdx.x >> 6;
    if (lane == 0) wsum[wid] = s;
    __syncthreads();
    if (threadIdx.x == 0) {
        const double mean = (wsum[0] + wsum[1] + wsum[2] + wsum[3]) / (double)((size_t)B_ * H_);
        const int c = (fabs(mean) > TOLC) ? 1 : 0;
        *active = c;
        if (!c) *done = 1;
    }
}

// fp32 -> (hi,lo) bf16 split, flat (for Wr)
__global__ __launch_bounds__(256)
void split_k(const float* __restrict__ x, ushort* __restrict__ hi,
             ushort* __restrict__ lo)
{
    const size_t i = (size_t)blockIdx.x * 256 + threadIdx.x;
    const float4 v = ((const float4*)x)[i];
    ushort4 h, l;
    h.x = f2bf(v.x); l.x = f2bf(v.x - bf2f(h.x));
    h.y = f2bf(v.y); l.y = f2bf(v.y - bf2f(h.y));
    h.z = f2bf(v.z); l.z = f2bf(v.z - bf2f(h.z));
    h.w = f2bf(v.w); l.w = f2bf(v.w - bf2f(h.w));
    ((ushort4*)hi)[i] = h;
    ((ushort4*)lo)[i] = l;
}

// prev0: split + per-row sum
__global__ __launch_bounds__(256)
void prev0_prep_k(const float* __restrict__ prev0, ushort* __restrict__ Phi,
                  ushort* __restrict__ Plo, float* __restrict__ prevsum0)
{
    const int b = blockIdx.x, tid = threadIdx.x;
    const size_t ro = (size_t)b * H_;
    const float4 v = ((const float4*)(prev0 + ro))[tid];
    ushort4 h, l;
    h.x = f2bf(v.x); l.x = f2bf(v.x - bf2f(h.x));
    h.y = f2bf(v.y); l.y = f2bf(v.y - bf2f(h.y));
    h.z = f2bf(v.z); l.z = f2bf(v.z - bf2f(h.z));
    h.w = f2bf(v.w); l.w = f2bf(v.w - bf2f(h.w));
    ((ushort4*)(Phi + ro))[tid] = h;
    ((ushort4*)(Plo + ro))[tid] = l;
    float sm = v.x + v.y + v.z + v.w;
#pragma unroll
    for (int off = 32; off > 0; off >>= 1) sm += __shfl_down(sm, off, 64);
    __shared__ float w2[4];
    const int lane = tid & 63, wid = tid >> 6;
    if (lane == 0) w2[wid] = sm;
    __syncthreads();
    if (tid == 0) prevsum0[b] = w2[0] + w2[1] + w2[2] + w2[3];
}

// Wout: split + transposed split (once)
__global__ __launch_bounds__(256)
void prep_wout_k(const float* __restrict__ Wout, ushort* __restrict__ Whi,
                 ushort* __restrict__ Wlo, ushort* __restrict__ WThi,
                 ushort* __restrict__ WTlo)
{
    const int idx = blockIdx.x * 256 + threadIdx.x;   // < NOBS*H_
    const float w = Wout[idx];
    const ushort h = f2bf(w), l = f2bf(w - bf2f(h));
    Whi[idx] = h; Wlo[idx] = l;
    const int o = idx >> 10, hh = idx & 1023;
    WThi[(size_t)hh * NOBS + o] = h;
    WTlo[(size_t)hh * NOBS + o] = l;
}

__global__ __launch_bounds__(256)
void copy_k(const float* __restrict__ src, float* __restrict__ dst)
{
    const size_t i = (size_t)blockIdx.x * 256 + threadIdx.x;
    ((float4*)dst)[i] = ((const float4*)src)[i];
}

__global__ void flags_init_k(int* flags) { flags[0] = 0; flags[1] = 0; }

// ---------------------------------------------------------------------------
extern "C" void kernel_launch(void* const* d_in, const int* in_sizes, int n_in,
                              void* d_out, int out_size, void* d_ws, size_t ws_size,
                              hipStream_t stream)
{
    const int*   dirs  = (const int*)d_in[0];
    const int*   obs   = (const int*)d_in[1];
    const float* Wr    = (const float*)d_in[2];
    const float* Win   = (const float*)d_in[3];
    const float* Wout  = (const float*)d_in[4];
    const float* prev0 = (const float*)d_in[5];
    float* out = (float*)d_out;

    const size_t SZ = (size_t)B_ * H_;
    float*  C    = (float*)d_ws;
    float*  T    = C + SZ;
    float*  part = T + SZ;                        // KS_ * B_ * NOBS
    ushort* Chi  = (ushort*)(part + (size_t)KS_ * B_ * NOBS);
    ushort* Clo  = Chi + SZ;
    ushort* Phi  = Clo + SZ;
    ushort* Plo  = Phi + SZ;
    ushort* Wrhi = Plo + SZ;
    ushort* Wrlo = Wrhi + (size_t)H_ * H_;
    ushort* Whi  = Wrlo + (size_t)H_ * H_;
    ushort* Wlo  = Whi + (size_t)NOBS * H_;
    ushort* WThi = Wlo + (size_t)NOBS * H_;
    ushort* WTlo = WThi + (size_t)H_ * NOBS;
    ushort* Jhi  = WTlo + (size_t)H_ * NOBS;
    ushort* Jlo  = Jhi + (size_t)B_ * NOBS;
    double* rowpart = (double*)(Jlo + (size_t)B_ * NOBS);
    float* prevsum0 = (float*)(rowpart + B_);
    float* rowsumC  = prevsum0 + B_;
    int* flags  = (int*)(rowsumC + B_);
    int* done   = flags;
    int* active = flags + 1;

    const dim3 blk(256);

    flags_init_k<<<1, 1, 0, stream>>>(flags);
    split_k<<<(H_ * H_ / 4) / 256, blk, 0, stream>>>(Wr, Wrhi, Wrlo);
    prev0_prep_k<<<B_, blk, 0, stream>>>(prev0, Phi, Plo, prevsum0);
    prep_wout_k<<<(NOBS * H_) / 256, blk, 0, stream>>>(Wout, Whi, Wlo, WThi, WTlo);

    // initial: T = relu(Wr@prev0 + drive); C = norm(T) (+ split + rowsums)
    mfma_gemm_k<<<dim3(H_ / 128, B_ / 128), blk, 0, stream>>>(
        Phi, Plo, Wrhi, Wrlo, T, dirs, Win, nullptr);
    normadv_k<false><<<B_, blk, 0, stream>>>(
        T, C, Chi, Clo, nullptr, nullptr, prevsum0, rowsumC, rowpart, nullptr);

    for (int it = 0; it < MAXIT; ++it) {
        cond_fin_k<<<1, blk, 0, stream>>>(rowpart, active, done);

        // R = relu(Wr@prev + drive) -> T.  At it==0, T already holds R_0.
        if (it > 0)
            mfma_gemm_k<<<dim3(H_ / 128, B_ / 128), blk, 0, stream>>>(
                Phi, Plo, Wrhi, Wrlo, T, dirs, Win, active);
        // logits partials from cur
        logits_mfma_k<<<dim3(KS_, B_ / 128), blk, 0, stream>>>(
            Chi, Clo, Whi, Wlo, part, active);
        // reduce + softmax + Jv (bf16 split)
        softjv_k<0><<<B_ / 4, blk, 0, stream>>>(part, obs, Jhi, Jlo, nullptr, active);
        // T = C + lr*((T - C) + Jv @ WoutT)
        epi3_mfma_k<<<dim3(H_ / 128, B_ / 128), blk, 0, stream>>>(
            Jhi, Jlo, WThi, WTlo, C, T, active);
        // prev <- cur (split copy); C <- norm(T); rowparts for next cond
        normadv_k<true><<<B_, blk, 0, stream>>>(
            T, C, Chi, Clo, Phi, Plo, rowsumC, rowsumC, rowpart, active);
    }

    // outputs: softmax(Wout @ cur), then cur
    logits_mfma_k<<<dim3(KS_, B_ / 128), blk, 0, stream>>>(
        Chi, Clo, Whi, Wlo, part, nullptr);
    softjv_k<1><<<B_ / 4, blk, 0, stream>>>(part, obs, nullptr, nullptr, out, nullptr);
    copy_k<<<SZ / 4 / 256, blk, 0, stream>>>(C, out + (size_t)B_ * NOBS);
}

// Round 4
// 314.291 us; speedup vs baseline: 2.4624x; 1.0517x over previous
//
#include <hip/hip_runtime.h>
#include <cstdint>
#include <cstddef>

#define B_    4096
#define H_    1024
#define NOBS  128
#define NDIR  64
#define MAXIT 10
#define LRI   1e-3f
#define TOLC  1e-3
#define KS_   8      // split-K factor for logits GEMM

typedef __bf16 bf16x8 __attribute__((ext_vector_type(8)));
typedef float  f32x4  __attribute__((ext_vector_type(4)));

__device__ __forceinline__ ushort f2bf(float x) {
    uint32_t u = __float_as_uint(x);
    u += 0x7FFFu + ((u >> 16) & 1u);   // RN-even to bf16
    return (ushort)(u >> 16);
}
__device__ __forceinline__ float bf2f(ushort h) {
    return __uint_as_float(((uint32_t)h) << 16);
}

// ---------------------------------------------------------------------------
// Stage one ROWSx32 bf16 tile into LDS via global_load_lds (16B/lane),
// with XOR-swizzled global source so the ds_read side is conflict-free.
// ---------------------------------------------------------------------------
template<int ROWS>
__device__ __forceinline__ void stage_tile(ushort* dst, const ushort* src,
                                           size_t rowbase, int ld, int k0,
                                           int tid, int wid)
{
    constexpr int ITERS = ROWS * 4 / 256;
#pragma unroll
    for (int cc = 0; cc < ITERS; ++cc) {
        const int c = cc * 256 + tid;
        const int r = c >> 2, s = c & 3;
        const int ks = ((s ^ ((r >> 1) & 3)) << 3);
        const ushort* g = src + (rowbase + r) * (size_t)ld + k0 + ks;
        __builtin_amdgcn_global_load_lds(
            (const __attribute__((address_space(1))) void*)g,
            (__attribute__((address_space(3))) void*)(dst + (cc * 256 + wid * 64) * 8),
            16, 0, 0);
    }
}

// ---------------------------------------------------------------------------
// Unified bf16x3 MFMA GEMM, 2-phase double-buffered pipeline.
// BM=128 rows, BN cols, BK=32, 4 waves (2Mx2N), wave = 4 x (BN/32) frags.
// EPI 0: O = relu(A@B^T + Win[col, dirs[row]])        (big Wr GEMM, BN=64)
// EPI 1: part[bx] = A@B^T K-chunk partial             (logits split-K, BN=128)
// EPI 2: T = Cin + LRI*((T - Cin) + A@B^T)            (update GEMM, BN=64)
// ---------------------------------------------------------------------------
template<int EPI, int BN>
__global__ __launch_bounds__(256)
void gemm_pipe_k(const ushort* __restrict__ Ahi, const ushort* __restrict__ Alo, int lda,
                 const ushort* __restrict__ Bhi, const ushort* __restrict__ Blo, int ldb,
                 float* __restrict__ O,
                 const int* __restrict__ dirs, const float* __restrict__ Win,
                 const float* __restrict__ Cin,
                 const int* gate)
{
    if (gate && *gate == 0) return;

    constexpr int NFR = BN / 32;                    // N frags per wave
    constexpr int NST = (EPI == 0) ? H_ / 32
                      : (EPI == 1) ? (H_ / KS_) / 32
                                   : NOBS / 32;     // K-steps

    __shared__ ushort sA[2][2][128 * 32];           // [buf][hi/lo]
    __shared__ ushort sB[2][2][BN * 32];

    const int tid = threadIdx.x, lane = tid & 63, wid = tid >> 6;
    const size_t m0  = (size_t)blockIdx.y * 128;
    const size_t bn0 = (EPI == 1) ? 0 : (size_t)blockIdx.x * BN;
    const int kbase  = (EPI == 1) ? blockIdx.x * (H_ / KS_) : 0;
    const int wr = wid >> 1, wc = wid & 1;

    f32x4 acc[4][NFR];
#pragma unroll
    for (int i = 0; i < 4; ++i)
#pragma unroll
        for (int j = 0; j < NFR; ++j) acc[i][j] = (f32x4){0.f, 0.f, 0.f, 0.f};

    const int rsel = lane & 15;
    const int kb   = lane >> 4;

    // prologue: stage tile 0
    stage_tile<128>(sA[0][0], Ahi, m0, lda, kbase, tid, wid);
    stage_tile<128>(sA[0][1], Alo, m0, lda, kbase, tid, wid);
    stage_tile<BN >(sB[0][0], Bhi, bn0, ldb, kbase, tid, wid);
    stage_tile<BN >(sB[0][1], Blo, bn0, ldb, kbase, tid, wid);
    __syncthreads();

#pragma unroll 2
    for (int t = 0; t < NST; ++t) {
        const int cur = t & 1;
        if (t + 1 < NST) {                          // prefetch tile t+1
            const int k0 = kbase + (t + 1) * 32;
            stage_tile<128>(sA[cur ^ 1][0], Ahi, m0, lda, k0, tid, wid);
            stage_tile<128>(sA[cur ^ 1][1], Alo, m0, lda, k0, tid, wid);
            stage_tile<BN >(sB[cur ^ 1][0], Bhi, bn0, ldb, k0, tid, wid);
            stage_tile<BN >(sB[cur ^ 1][1], Blo, bn0, ldb, k0, tid, wid);
        }

        bf16x8 ah[4], al[4], bh[NFR], bl[NFR];
#pragma unroll
        for (int f = 0; f < 4; ++f) {
            const int arow = wr * 64 + f * 16 + rsel;
            const int aoff = arow * 32 + ((kb ^ ((arow >> 1) & 3)) << 3);
            ah[f] = *(const bf16x8*)&sA[cur][0][aoff];
            al[f] = *(const bf16x8*)&sA[cur][1][aoff];
        }
#pragma unroll
        for (int f = 0; f < NFR; ++f) {
            const int brow = wc * (BN / 2) + f * 16 + rsel;
            const int boff = brow * 32 + ((kb ^ ((brow >> 1) & 3)) << 3);
            bh[f] = *(const bf16x8*)&sB[cur][0][boff];
            bl[f] = *(const bf16x8*)&sB[cur][1][boff];
        }

#pragma unroll
        for (int i = 0; i < 4; ++i)
#pragma unroll
            for (int j = 0; j < NFR; ++j) {
                acc[i][j] = __builtin_amdgcn_mfma_f32_16x16x32_bf16(ah[i], bh[j], acc[i][j], 0, 0, 0);
                acc[i][j] = __builtin_amdgcn_mfma_f32_16x16x32_bf16(ah[i], bl[j], acc[i][j], 0, 0, 0);
                acc[i][j] = __builtin_amdgcn_mfma_f32_16x16x32_bf16(al[i], bh[j], acc[i][j], 0, 0, 0);
            }
        __syncthreads();   // drains vmcnt(0): prefetch t+1 complete, buf read done
    }

    // epilogue: C/D layout col=lane&15, row=(lane>>4)*4+r
    float* pout = (EPI == 1) ? O + (size_t)blockIdx.x * B_ * NOBS : O;
#pragma unroll
    for (int i = 0; i < 4; ++i) {
#pragma unroll
        for (int r = 0; r < 4; ++r) {
            const size_t row = m0 + wr * 64 + i * 16 + (lane >> 4) * 4 + r;
            int dd = 0;
            if (EPI == 0) dd = dirs[row];
#pragma unroll
            for (int j = 0; j < NFR; ++j) {
                const size_t col = bn0 + wc * (BN / 2) + j * 16 + (lane & 15);
                if (EPI == 0) {
                    const float v = acc[i][j][r] + Win[col * NDIR + dd];
                    pout[row * H_ + col] = fmaxf(v, 0.f);
                } else if (EPI == 1) {
                    pout[row * NOBS + col] = acc[i][j][r];
                } else {
                    const size_t idx = row * H_ + col;
                    const float c = Cin[idx], rv = pout[idx];
                    pout[idx] = c + LRI * ((rv - c) + acc[i][j][r]);
                }
            }
        }
    }
}

// ---------------------------------------------------------------------------
// Reduce split-K partials -> logits; softmax.
// MODE 0: + Jacobian-vector product, write Jv bf16 split (gated).
// MODE 1: write probabilities to out (ungated, final).
// ---------------------------------------------------------------------------
template<int MODE>
__global__ __launch_bounds__(256)
void softjv_k(const float* __restrict__ part, const int* __restrict__ obs,
              ushort* __restrict__ Jhi, ushort* __restrict__ Jlo,
              float* __restrict__ probs, const int* gate)
{
    if (MODE == 0 && gate && *gate == 0) return;
    const int wid = threadIdx.x >> 6, lane = threadIdx.x & 63;
    const int b = blockIdx.x * 4 + wid;
    float x0 = 0.f, x1 = 0.f;
#pragma unroll
    for (int kb = 0; kb < KS_; ++kb) {
        const float* p = part + ((size_t)kb * B_ + b) * NOBS;
        x0 += p[lane]; x1 += p[lane + 64];
    }
    float mx = fmaxf(x0, x1);
#pragma unroll
    for (int off = 32; off > 0; off >>= 1) mx = fmaxf(mx, __shfl_xor(mx, off, 64));
    const float e0 = expf(x0 - mx), e1 = expf(x1 - mx);
    float s = e0 + e1;
#pragma unroll
    for (int off = 32; off > 0; off >>= 1) s += __shfl_xor(s, off, 64);
    const float f0 = e0 / s, f1 = e1 / s;
    if (MODE == 1) {
        probs[(size_t)b * NOBS + lane]      = f0;
        probs[(size_t)b * NOBS + lane + 64] = f1;
        return;
    }
    const int o = obs[b];
    const float ep0 = ((lane == o) ? 1.f : 0.f) - f0;
    const float ep1 = ((lane + 64 == o) ? 1.f : 0.f) - f1;
    float d = f0 * ep0 + f1 * ep1;
#pragma unroll
    for (int off = 32; off > 0; off >>= 1) d += __shfl_xor(d, off, 64);
    const float j0 = f0 * (ep0 - d), j1 = f1 * (ep1 - d);
    const ushort h0 = f2bf(j0), h1 = f2bf(j1);
    Jhi[(size_t)b * NOBS + lane]      = h0;
    Jlo[(size_t)b * NOBS + lane]      = f2bf(j0 - bf2f(h0));
    Jhi[(size_t)b * NOBS + lane + 64] = h1;
    Jlo[(size_t)b * NOBS + lane + 64] = f2bf(j1 - bf2f(h1));
}

// ---------------------------------------------------------------------------
// Fused advance + row-normalize (+ per-row sums for the convergence gate).
// ---------------------------------------------------------------------------
template<bool ADV>
__global__ __launch_bounds__(256)
void normadv_k(const float* __restrict__ T, float* __restrict__ C,
               ushort* __restrict__ Chi, ushort* __restrict__ Clo,
               ushort* __restrict__ Phi, ushort* __restrict__ Plo,
               const float* __restrict__ oldsum, float* __restrict__ rowsum,
               double* __restrict__ rowpart, const int* gate)
{
    if (gate && *gate == 0) return;
    const int b = blockIdx.x, tid = threadIdx.x;
    const size_t ro = (size_t)b * H_;

    if (ADV) {
        ((ushort4*)(Phi + ro))[tid] = ((const ushort4*)(Chi + ro))[tid];
        ((ushort4*)(Plo + ro))[tid] = ((const ushort4*)(Clo + ro))[tid];
    }

    const float4 v = ((const float4*)(T + ro))[tid];
    float ss = v.x * v.x + v.y * v.y + v.z * v.z + v.w * v.w;
    float sm = v.x + v.y + v.z + v.w;
#pragma unroll
    for (int off = 32; off > 0; off >>= 1) {
        ss += __shfl_down(ss, off, 64);
        sm += __shfl_down(sm, off, 64);
    }
    __shared__ float w1[4], w2[4];
    const int lane = tid & 63, wid = tid >> 6;
    if (lane == 0) { w1[wid] = ss; w2[wid] = sm; }
    __syncthreads();
    const float tot = w1[0] + w1[1] + w1[2] + w1[3];
    const float smt = w2[0] + w2[1] + w2[2] + w2[3];
    const float d = sqrtf(tot) + 1e-6f;

    float4 o;
    o.x = v.x / d; o.y = v.y / d; o.z = v.z / d; o.w = v.w / d;
    ((float4*)(C + ro))[tid] = o;
    ushort4 h, l;
    h.x = f2bf(o.x); l.x = f2bf(o.x - bf2f(h.x));
    h.y = f2bf(o.y); l.y = f2bf(o.y - bf2f(h.y));
    h.z = f2bf(o.z); l.z = f2bf(o.z - bf2f(h.z));
    h.w = f2bf(o.w); l.w = f2bf(o.w - bf2f(h.w));
    ((ushort4*)(Chi + ro))[tid] = h;
    ((ushort4*)(Clo + ro))[tid] = l;

    if (tid == 0) {
        const float news = smt / d;
        rowpart[b] = (double)oldsum[b] - (double)news;
        rowsum[b]  = news;
    }
}

// finalize cond: reduce 4096 row partials, set active/done (sticky)
__global__ __launch_bounds__(256)
void cond_fin_k(const double* __restrict__ rowpart, int* active, int* done)
{
    if (*done) { if (threadIdx.x == 0) *active = 0; return; }
    __shared__ double wsum[4];
    double s = 0.0;
    for (int i = threadIdx.x; i < B_; i += 256) s += rowpart[i];
#pragma unroll
    for (int off = 32; off > 0; off >>= 1) s += __shfl_down(s, off, 64);
    const int lane = threadIdx.x & 63, wid = threadIdx.x >> 6;
    if (lane == 0) wsum[wid] = s;
    __syncthreads();
    if (threadIdx.x == 0) {
        const double mean = (wsum[0] + wsum[1] + wsum[2] + wsum[3]) / (double)((size_t)B_ * H_);
        const int c = (fabs(mean) > TOLC) ? 1 : 0;
        *active = c;
        if (!c) *done = 1;
    }
}

// fp32 -> (hi,lo) bf16 split, flat (for Wr)
__global__ __launch_bounds__(256)
void split_k(const float* __restrict__ x, ushort* __restrict__ hi,
             ushort* __restrict__ lo)
{
    const size_t i = (size_t)blockIdx.x * 256 + threadIdx.x;
    const float4 v = ((const float4*)x)[i];
    ushort4 h, l;
    h.x = f2bf(v.x); l.x = f2bf(v.x - bf2f(h.x));
    h.y = f2bf(v.y); l.y = f2bf(v.y - bf2f(h.y));
    h.z = f2bf(v.z); l.z = f2bf(v.z - bf2f(h.z));
    h.w = f2bf(v.w); l.w = f2bf(v.w - bf2f(h.w));
    ((ushort4*)hi)[i] = h;
    ((ushort4*)lo)[i] = l;
}

// prev0: split + per-row sum
__global__ __launch_bounds__(256)
void prev0_prep_k(const float* __restrict__ prev0, ushort* __restrict__ Phi,
                  ushort* __restrict__ Plo, float* __restrict__ prevsum0)
{
    const int b = blockIdx.x, tid = threadIdx.x;
    const size_t ro = (size_t)b * H_;
    const float4 v = ((const float4*)(prev0 + ro))[tid];
    ushort4 h, l;
    h.x = f2bf(v.x); l.x = f2bf(v.x - bf2f(h.x));
    h.y = f2bf(v.y); l.y = f2bf(v.y - bf2f(h.y));
    h.z = f2bf(v.z); l.z = f2bf(v.z - bf2f(h.z));
    h.w = f2bf(v.w); l.w = f2bf(v.w - bf2f(h.w));
    ((ushort4*)(Phi + ro))[tid] = h;
    ((ushort4*)(Plo + ro))[tid] = l;
    float sm = v.x + v.y + v.z + v.w;
#pragma unroll
    for (int off = 32; off > 0; off >>= 1) sm += __shfl_down(sm, off, 64);
    __shared__ float w2[4];
    const int lane = tid & 63, wid = tid >> 6;
    if (lane == 0) w2[wid] = sm;
    __syncthreads();
    if (tid == 0) prevsum0[b] = w2[0] + w2[1] + w2[2] + w2[3];
}

// Wout: split + transposed split (once)
__global__ __launch_bounds__(256)
void prep_wout_k(const float* __restrict__ Wout, ushort* __restrict__ Whi,
                 ushort* __restrict__ Wlo, ushort* __restrict__ WThi,
                 ushort* __restrict__ WTlo)
{
    const int idx = blockIdx.x * 256 + threadIdx.x;   // < NOBS*H_
    const float w = Wout[idx];
    const ushort h = f2bf(w), l = f2bf(w - bf2f(h));
    Whi[idx] = h; Wlo[idx] = l;
    const int o = idx >> 10, hh = idx & 1023;
    WThi[(size_t)hh * NOBS + o] = h;
    WTlo[(size_t)hh * NOBS + o] = l;
}

__global__ __launch_bounds__(256)
void copy_k(const float* __restrict__ src, float* __restrict__ dst)
{
    const size_t i = (size_t)blockIdx.x * 256 + threadIdx.x;
    ((float4*)dst)[i] = ((const float4*)src)[i];
}

__global__ void flags_init_k(int* flags) { flags[0] = 0; flags[1] = 0; }

// ---------------------------------------------------------------------------
extern "C" void kernel_launch(void* const* d_in, const int* in_sizes, int n_in,
                              void* d_out, int out_size, void* d_ws, size_t ws_size,
                              hipStream_t stream)
{
    const int*   dirs  = (const int*)d_in[0];
    const int*   obs   = (const int*)d_in[1];
    const float* Wr    = (const float*)d_in[2];
    const float* Win   = (const float*)d_in[3];
    const float* Wout  = (const float*)d_in[4];
    const float* prev0 = (const float*)d_in[5];
    float* out = (float*)d_out;

    const size_t SZ = (size_t)B_ * H_;
    float*  C    = (float*)d_ws;
    float*  T    = C + SZ;
    float*  part = T + SZ;                        // KS_ * B_ * NOBS
    ushort* Chi  = (ushort*)(part + (size_t)KS_ * B_ * NOBS);
    ushort* Clo  = Chi + SZ;
    ushort* Phi  = Clo + SZ;
    ushort* Plo  = Phi + SZ;
    ushort* Wrhi = Plo + SZ;
    ushort* Wrlo = Wrhi + (size_t)H_ * H_;
    ushort* Whi  = Wrlo + (size_t)H_ * H_;
    ushort* Wlo  = Whi + (size_t)NOBS * H_;
    ushort* WThi = Wlo + (size_t)NOBS * H_;
    ushort* WTlo = WThi + (size_t)H_ * NOBS;
    ushort* Jhi  = WTlo + (size_t)H_ * NOBS;
    ushort* Jlo  = Jhi + (size_t)B_ * NOBS;
    double* rowpart = (double*)(Jlo + (size_t)B_ * NOBS);
    float* prevsum0 = (float*)(rowpart + B_);
    float* rowsumC  = prevsum0 + B_;
    int* flags  = (int*)(rowsumC + B_);
    int* done   = flags;
    int* active = flags + 1;

    const dim3 blk(256);
    const dim3 gBig(H_ / 64, B_ / 128);    // 512 blocks, BN=64
    const dim3 gLog(KS_, B_ / 128);        // 256 blocks, BN=128

    flags_init_k<<<1, 1, 0, stream>>>(flags);
    split_k<<<(H_ * H_ / 4) / 256, blk, 0, stream>>>(Wr, Wrhi, Wrlo);
    prev0_prep_k<<<B_, blk, 0, stream>>>(prev0, Phi, Plo, prevsum0);
    prep_wout_k<<<(NOBS * H_) / 256, blk, 0, stream>>>(Wout, Whi, Wlo, WThi, WTlo);

    // initial: T = relu(Wr@prev0 + drive); C = norm(T) (+ split + rowsums)
    gemm_pipe_k<0, 64><<<gBig, blk, 0, stream>>>(
        Phi, Plo, H_, Wrhi, Wrlo, H_, T, dirs, Win, nullptr, nullptr);
    normadv_k<false><<<B_, blk, 0, stream>>>(
        T, C, Chi, Clo, nullptr, nullptr, prevsum0, rowsumC, rowpart, nullptr);

    for (int it = 0; it < MAXIT; ++it) {
        cond_fin_k<<<1, blk, 0, stream>>>(rowpart, active, done);

        // R = relu(Wr@prev + drive) -> T.  At it==0, T already holds R_0.
        if (it > 0)
            gemm_pipe_k<0, 64><<<gBig, blk, 0, stream>>>(
                Phi, Plo, H_, Wrhi, Wrlo, H_, T, dirs, Win, nullptr, active);
        // logits partials from cur
        gemm_pipe_k<1, 128><<<gLog, blk, 0, stream>>>(
            Chi, Clo, H_, Whi, Wlo, H_, part, nullptr, nullptr, nullptr, active);
        // reduce + softmax + Jv (bf16 split)
        softjv_k<0><<<B_ / 4, blk, 0, stream>>>(part, obs, Jhi, Jlo, nullptr, active);
        // T = C + lr*((T - C) + Jv @ WoutT)
        gemm_pipe_k<2, 64><<<gBig, blk, 0, stream>>>(
            Jhi, Jlo, NOBS, WThi, WTlo, NOBS, T, nullptr, nullptr, C, active);
        // prev <- cur (split copy); C <- norm(T); rowparts for next cond
        normadv_k<true><<<B_, blk, 0, stream>>>(
            T, C, Chi, Clo, Phi, Plo, rowsumC, rowsumC, rowpart, active);
    }

    // outputs: softmax(Wout @ cur), then cur
    gemm_pipe_k<1, 128><<<gLog, blk, 0, stream>>>(
        Chi, Clo, H_, Whi, Wlo, H_, part, nullptr, nullptr, nullptr, nullptr);
    softjv_k<1><<<B_ / 4, blk, 0, stream>>>(part, obs, nullptr, nullptr, out, nullptr);
    copy_k<<<SZ / 4 / 256, blk, 0, stream>>>(C, out + (size_t)B_ * NOBS);
}